// Round 4
// baseline (7515.268 us; speedup 1.0000x reference)
//
#include <hip/hip_runtime.h>
#include <math.h>

#define NRES 512
#define CC   128
#define LN_EPS 1e-5f

// ---------------------------------------------------------------------------
// DIAGNOSTIC BUILD: reference-faithful fp32, no MFMA, no fp16, no swizzles.
// Purpose: attribute the persistent ~3e-2 structural error. Keep it simple.
// ---------------------------------------------------------------------------

__device__ __forceinline__ float block_sum_128(float v, float* red, int t) {
    #pragma unroll
    for (int s = 1; s < 64; s <<= 1) v += __shfl_xor(v, s);
    __syncthreads();                 // protect red[] from previous use
    if ((t & 63) == 0) red[t >> 6] = v;
    __syncthreads();
    return red[0] + red[1];
}

// One block (128 threads) per row-block i. Computes S[i,:] = sum_j g*x1 for
// one side. Explicit per-side launch: no side multiplexing anywhere.
__global__ __launch_bounds__(128)
void phaseA_fp32(const float* __restrict__ X, const float* __restrict__ mask,
                 const float* __restrict__ Wp, const float* __restrict__ bp,
                 const float* __restrict__ Wg, const float* __restrict__ bg,
                 const float* __restrict__ lnw, const float* __restrict__ lnb,
                 const int use_mask, float* __restrict__ S)
{
    __shared__ float Wpt[CC*CC];     // transposed [k][o] for conflict-free reads
    __shared__ float Wgt[CC*CC];
    __shared__ float aS[CC];
    __shared__ float x1S[CC];
    __shared__ float red[2];
    __shared__ float bpS[CC], bgS[CC], lnwS[CC], lnbS[CC];

    const int t = threadIdx.x;
    const int i = blockIdx.x;

    for (int idx = t; idx < CC*CC; idx += 128) {
        const int o = idx >> 7, k = idx & 127;
        Wpt[k*CC + o] = Wp[idx];     // Wp is [o][k] row-major (torch [out,in])
        Wgt[k*CC + o] = Wg[idx];
    }
    bpS[t] = bp[t]; bgS[t] = bg[t]; lnwS[t] = lnw[t]; lnbS[t] = lnb[t];
    __syncthreads();

    float acc = 0.f;
    for (int j = 0; j < NRES; ++j) {
        // LayerNorm of X[i,j,:] (exact reference form)
        const float x = X[((size_t)i*NRES + j)*CC + t];
        const float m = block_sum_128(x, red, t) * (1.f/CC);
        const float d = x - m;
        const float var = block_sum_128(d*d, red, t) * (1.f/CC);
        const float rs = rsqrtf(var + LN_EPS);
        aS[t] = d * rs * lnwS[t] + lnbS[t];
        __syncthreads();

        // x1[o] = a . Wp[o,:] + bp[o]   (then mask for the z-side)
        float d0=0.f,d1=0.f,d2=0.f,d3=0.f;
        #pragma unroll
        for (int k = 0; k < CC; k += 4) {
            d0 += aS[k+0]*Wpt[(k+0)*CC + t];
            d1 += aS[k+1]*Wpt[(k+1)*CC + t];
            d2 += aS[k+2]*Wpt[(k+2)*CC + t];
            d3 += aS[k+3]*Wpt[(k+3)*CC + t];
        }
        float x1 = ((d0+d1)+(d2+d3)) + bpS[t];
        if (use_mask) x1 *= mask[(size_t)i*NRES + j];
        __syncthreads();             // all lanes done reading aS
        x1S[t] = x1;
        __syncthreads();

        // g[o] = sigmoid(x1 . Wg[o,:] + bg[o]);  acc += g*x1
        float e0=0.f,e1=0.f,e2=0.f,e3=0.f;
        #pragma unroll
        for (int k = 0; k < CC; k += 4) {
            e0 += x1S[k+0]*Wgt[(k+0)*CC + t];
            e1 += x1S[k+1]*Wgt[(k+1)*CC + t];
            e2 += x1S[k+2]*Wgt[(k+2)*CC + t];
            e3 += x1S[k+3]*Wgt[(k+3)*CC + t];
        }
        const float gi = ((e0+e1)+(e2+e3)) + bgS[t];
        const float g  = 1.f / (1.f + expf(-gi));
        acc += g * x1;
        __syncthreads();             // x1S consumed before next iteration
    }
    S[(size_t)i*CC + t] = acc;
}

// One block (128 threads) per (i, 64-row j-chunk).
// out[i,j,:] = LN(zl[i] * zr[j]) . Wz^T + bz
__global__ __launch_bounds__(128)
void phaseB_fp32(const float* __restrict__ zl, const float* __restrict__ zr,
                 const float* __restrict__ Wz, const float* __restrict__ bz,
                 const float* __restrict__ lnw, const float* __restrict__ lnb,
                 float* __restrict__ out)
{
    __shared__ float Wzt[CC*CC];
    __shared__ float aS[CC];
    __shared__ float red[2];
    __shared__ float zlS[CC], bzS[CC], lnwS[CC], lnbS[CC];

    const int t  = threadIdx.x;
    const int i  = blockIdx.x >> 3;
    const int j0 = (blockIdx.x & 7) * 64;

    for (int idx = t; idx < CC*CC; idx += 128) {
        const int o = idx >> 7, k = idx & 127;
        Wzt[k*CC + o] = Wz[idx];
    }
    zlS[t] = zl[(size_t)i*CC + t];
    bzS[t] = bz[t]; lnwS[t] = lnw[t]; lnbS[t] = lnb[t];
    __syncthreads();

    for (int jj = 0; jj < 64; ++jj) {
        const int j = j0 + jj;
        const float x = zr[(size_t)j*CC + t] * zlS[t];
        const float m = block_sum_128(x, red, t) * (1.f/CC);
        const float d = x - m;
        const float var = block_sum_128(d*d, red, t) * (1.f/CC);
        const float rs = rsqrtf(var + LN_EPS);
        aS[t] = d * rs * lnwS[t] + lnbS[t];
        __syncthreads();

        float d0=0.f,d1=0.f,d2=0.f,d3=0.f;
        #pragma unroll
        for (int k = 0; k < CC; k += 4) {
            d0 += aS[k+0]*Wzt[(k+0)*CC + t];
            d1 += aS[k+1]*Wzt[(k+1)*CC + t];
            d2 += aS[k+2]*Wzt[(k+2)*CC + t];
            d3 += aS[k+3]*Wzt[(k+3)*CC + t];
        }
        out[((size_t)i*NRES + j)*CC + t] = ((d0+d1)+(d2+d3)) + bzS[t];
        __syncthreads();             // aS consumed before next iteration
    }
}

extern "C" void kernel_launch(void* const* d_in, const int* in_sizes, int n_in,
                              void* d_out, int out_size, void* d_ws, size_t ws_size,
                              hipStream_t stream)
{
    (void)in_sizes; (void)n_in; (void)out_size; (void)ws_size;
    const float* z      = (const float*)d_in[0];
    const float* p      = (const float*)d_in[1];
    const float* mask   = (const float*)d_in[2];
    const float* w_lp   = (const float*)d_in[3];
    const float* b_lp   = (const float*)d_in[4];
    const float* w_rp   = (const float*)d_in[5];
    const float* b_rp   = (const float*)d_in[6];
    const float* w_lg   = (const float*)d_in[7];
    const float* b_lg   = (const float*)d_in[8];
    const float* w_rg   = (const float*)d_in[9];
    const float* b_rg   = (const float*)d_in[10];
    const float* w_z    = (const float*)d_in[11];
    const float* b_z    = (const float*)d_in[12];
    const float* ln_l_w = (const float*)d_in[13];
    const float* ln_l_b = (const float*)d_in[14];
    const float* ln_r_w = (const float*)d_in[15];
    const float* ln_r_b = (const float*)d_in[16];
    const float* ln_o_w = (const float*)d_in[17];
    const float* ln_o_b = (const float*)d_in[18];
    float* out = (float*)d_out;

    float* zl = (float*)d_ws;              // [512][128]
    float* zr = zl + NRES*CC;              // [512][128]

    // side l: X = p, no mask  -> zl
    phaseA_fp32<<<dim3(NRES), dim3(128), 0, stream>>>(
        p, mask, w_lp, b_lp, w_lg, b_lg, ln_l_w, ln_l_b, 0, zl);

    // side r: X = z, masked   -> zr
    phaseA_fp32<<<dim3(NRES), dim3(128), 0, stream>>>(
        z, mask, w_rp, b_rp, w_rg, b_rg, ln_r_w, ln_r_b, 1, zr);

    phaseB_fp32<<<dim3(NRES*8), dim3(128), 0, stream>>>(
        zl, zr, w_z, b_z, ln_o_w, ln_o_b, out);
}

// Round 6
// 1335.119 us; speedup vs baseline: 5.6289x; 5.6289x over previous
//
#include <hip/hip_runtime.h>
#include <hip/hip_bf16.h>
#include <math.h>

#define NRES 512
#define CC   128
#define LN_EPS 1e-5f

typedef _Float16 half_t;
typedef __attribute__((ext_vector_type(8))) _Float16 f16x8;
typedef __attribute__((ext_vector_type(4))) float f32x4;

__device__ __forceinline__ float sigmoidf_(float x) {
    return 1.0f / (1.0f + expf(-x));
}

// ---------------------------------------------------------------------------
// Phase A (MFMA): identical math to round 5, but with full __syncthreads()
// at every stage boundary instead of the zero-barrier wave-self-contained
// scheme. Single-variable experiment: does explicit sync fix the ~3e-2
// structural error?
// ---------------------------------------------------------------------------
__global__ __launch_bounds__(512)
void phaseA_kernel(const float* __restrict__ p, const float* __restrict__ z,
                   const float* __restrict__ mask,
                   const float* __restrict__ Wlp, const float* __restrict__ blp,
                   const float* __restrict__ Wlg, const float* __restrict__ blg,
                   const float* __restrict__ Wrp, const float* __restrict__ brp,
                   const float* __restrict__ Wrg, const float* __restrict__ brg,
                   const float* __restrict__ lnlw, const float* __restrict__ lnlb,
                   const float* __restrict__ lnrw, const float* __restrict__ lnrb,
                   float* __restrict__ SL)
{
    __shared__ __align__(16) half_t sWp[CC*CC];
    __shared__ __align__(16) half_t sWg[CC*CC];
    __shared__ __align__(16) half_t sA [128*CC];
    __shared__ __align__(16) half_t sX1[128*CC];
    __shared__ float sbp[CC], sbg[CC], slnw[CC], slnb[CC];
    __shared__ float smask[NRES];
    __shared__ float sred[8][CC];

    const int t    = threadIdx.x;
    const int side = blockIdx.x >> 9;
    const int i    = blockIdx.x & 511;
    const int lane = t & 63;
    const int w    = t >> 6;

    const float* X   = side ? z   : p;
    const float* Wp  = side ? Wrp : Wlp;
    const float* bp  = side ? brp : blp;
    const float* Wg  = side ? Wrg : Wlg;
    const float* bg  = side ? brg : blg;
    const float* lnw = side ? lnrw : lnlw;
    const float* lnb = side ? lnrb : lnlb;
    const bool   use_mask = (side != 0);

    {
        const int o = t >> 2, q = t & 3;
        const float* wp_row = Wp + o * CC;
        const float* wg_row = Wg + o * CC;
        #pragma unroll
        for (int b = 0; b < 4; ++b) {
            const int blk  = q * 4 + b;
            const int dblk = blk ^ (o & 7);
            f32x4 lo  = *(const f32x4*)(wp_row + blk*8);
            f32x4 hi  = *(const f32x4*)(wp_row + blk*8 + 4);
            f32x4 lo2 = *(const f32x4*)(wg_row + blk*8);
            f32x4 hi2 = *(const f32x4*)(wg_row + blk*8 + 4);
            f16x8 v, v2;
            #pragma unroll
            for (int e = 0; e < 4; ++e) {
                v[e]    = (half_t)lo[e];  v[e+4]  = (half_t)hi[e];
                v2[e]   = (half_t)lo2[e]; v2[e+4] = (half_t)hi2[e];
            }
            *(f16x8*)&sWp[o*CC + dblk*8] = v;
            *(f16x8*)&sWg[o*CC + dblk*8] = v2;
        }
    }
    if (t < CC) { sbp[t] = bp[t]; sbg[t] = bg[t]; slnw[t] = lnw[t]; slnb[t] = lnb[t]; }
    if (use_mask) {
        for (int j = t; j < NRES; j += 512) smask[j] = mask[(size_t)i*NRES + j];
    }
    __syncthreads();

    float colacc[8];
    #pragma unroll
    for (int c = 0; c < 8; ++c) colacc[c] = 0.f;

    const int r     = t >> 2;
    const int q     = t & 3;
    const int kq    = lane >> 4;
    const int arow  = (w << 4) + (lane & 15);
    const int drow0 = (w << 4) + (kq << 2);

    for (int chunk = 0; chunk < 4; ++chunk) {
        const int j0 = chunk * 128;

        {
            const float* rowp = X + ((size_t)i*NRES + (j0 + r)) * CC + q*32;
            float vals[32];
            float sum = 0.f, sq = 0.f;
            #pragma unroll
            for (int k = 0; k < 8; ++k) {
                f32x4 v4 = *(const f32x4*)(rowp + k*4);
                #pragma unroll
                for (int e = 0; e < 4; ++e) {
                    float x = v4[e];
                    vals[k*4+e] = x;
                    sum += x; sq += x*x;
                }
            }
            sum += __shfl_xor(sum, 1); sum += __shfl_xor(sum, 2);
            sq  += __shfl_xor(sq , 1); sq  += __shfl_xor(sq , 2);
            const float m  = sum * (1.f/CC);
            const float rs = rsqrtf(sq * (1.f/CC) - m*m + LN_EPS);
            #pragma unroll
            for (int b = 0; b < 4; ++b) {
                f16x8 o8;
                #pragma unroll
                for (int e = 0; e < 8; ++e) {
                    const int c = q*32 + b*8 + e;
                    o8[e] = (half_t)((vals[b*8+e] - m) * rs * slnw[c] + slnb[c]);
                }
                const int blk = q*4 + b;
                *(f16x8*)&sA[r*CC + (blk ^ (r & 7))*8] = o8;
            }
        }
        __syncthreads();   // LN stores visible to all before fragment loads

        f16x8 af[4];
        #pragma unroll
        for (int kk = 0; kk < 4; ++kk)
            af[kk] = *(const f16x8*)&sA[arow*CC + ((((kk<<2)+kq)) ^ (arow & 7))*8];

        float xv[8][4];
        float mrow[4];
        if (use_mask) {
            #pragma unroll
            for (int rr = 0; rr < 4; ++rr) mrow[rr] = smask[j0 + drow0 + rr];
        }
        #pragma unroll
        for (int ct = 0; ct < 8; ++ct) {
            const int ocol = (ct << 4) + (lane & 15);
            f32x4 acc = {0.f, 0.f, 0.f, 0.f};
            #pragma unroll
            for (int kk = 0; kk < 4; ++kk) {
                f16x8 bfr = *(const f16x8*)&sWp[ocol*CC + ((((kk<<2)+kq)) ^ (ocol & 7))*8];
                acc = __builtin_amdgcn_mfma_f32_16x16x32_f16(af[kk], bfr, acc, 0, 0, 0);
            }
            const float bias = sbp[ocol];
            #pragma unroll
            for (int rr = 0; rr < 4; ++rr) {
                float x = acc[rr] + bias;
                if (use_mask) x *= mrow[rr];
                xv[ct][rr] = x;
                const int dr = drow0 + rr;
                sX1[dr*CC + (((ocol>>3) ^ (dr & 7))<<3) + (ocol & 7)] = (half_t)x;
            }
        }
        __syncthreads();   // X1 stores visible to all before pass-2 loads

        f16x8 a2[4];
        #pragma unroll
        for (int kk = 0; kk < 4; ++kk)
            a2[kk] = *(const f16x8*)&sX1[arow*CC + ((((kk<<2)+kq)) ^ (arow & 7))*8];
        #pragma unroll
        for (int ct = 0; ct < 8; ++ct) {
            const int ocol = (ct << 4) + (lane & 15);
            f32x4 acc = {0.f, 0.f, 0.f, 0.f};
            #pragma unroll
            for (int kk = 0; kk < 4; ++kk) {
                f16x8 bfr = *(const f16x8*)&sWg[ocol*CC + ((((kk<<2)+kq)) ^ (ocol & 7))*8];
                acc = __builtin_amdgcn_mfma_f32_16x16x32_f16(a2[kk], bfr, acc, 0, 0, 0);
            }
            const float bias = sbg[ocol];
            float part = 0.f;
            #pragma unroll
            for (int rr = 0; rr < 4; ++rr)
                part += sigmoidf_(acc[rr] + bias) * xv[ct][rr];
            part += __shfl_xor(part, 16);
            part += __shfl_xor(part, 32);
            colacc[ct] += part;
        }
        __syncthreads();   // pass-2 loads complete before next chunk overwrites
    }

    if (lane < 16) {
        #pragma unroll
        for (int ct = 0; ct < 8; ++ct) sred[w][(ct<<4) + lane] = colacc[ct];
    }
    __syncthreads();
    if (t < CC) {
        float s = 0.f;
        #pragma unroll
        for (int ww = 0; ww < 8; ++ww) s += sred[ww][t];
        SL[((size_t)side*NRES + i)*CC + t] = s;
    }
}

// ---------------------------------------------------------------------------
// Phase B (fp32, verbatim round-4 PASSING kernel)
// ---------------------------------------------------------------------------
__device__ __forceinline__ float block_sum_128(float v, float* red, int t) {
    #pragma unroll
    for (int s = 1; s < 64; s <<= 1) v += __shfl_xor(v, s);
    __syncthreads();
    if ((t & 63) == 0) red[t >> 6] = v;
    __syncthreads();
    return red[0] + red[1];
}

__global__ __launch_bounds__(128)
void phaseB_fp32(const float* __restrict__ zl, const float* __restrict__ zr,
                 const float* __restrict__ Wz, const float* __restrict__ bz,
                 const float* __restrict__ lnw, const float* __restrict__ lnb,
                 float* __restrict__ out)
{
    __shared__ float Wzt[CC*CC];
    __shared__ float aS[CC];
    __shared__ float red[2];
    __shared__ float zlS[CC], bzS[CC], lnwS[CC], lnbS[CC];

    const int t  = threadIdx.x;
    const int i  = blockIdx.x >> 3;
    const int j0 = (blockIdx.x & 7) * 64;

    for (int idx = t; idx < CC*CC; idx += 128) {
        const int o = idx >> 7, k = idx & 127;
        Wzt[k*CC + o] = Wz[idx];
    }
    zlS[t] = zl[(size_t)i*CC + t];
    bzS[t] = bz[t]; lnwS[t] = lnw[t]; lnbS[t] = lnb[t];
    __syncthreads();

    for (int jj = 0; jj < 64; ++jj) {
        const int j = j0 + jj;
        const float x = zr[(size_t)j*CC + t] * zlS[t];
        const float m = block_sum_128(x, red, t) * (1.f/CC);
        const float d = x - m;
        const float var = block_sum_128(d*d, red, t) * (1.f/CC);
        const float rs = rsqrtf(var + LN_EPS);
        aS[t] = d * rs * lnwS[t] + lnbS[t];
        __syncthreads();

        float d0=0.f,d1=0.f,d2=0.f,d3=0.f;
        #pragma unroll
        for (int k = 0; k < CC; k += 4) {
            d0 += aS[k+0]*Wzt[(k+0)*CC + t];
            d1 += aS[k+1]*Wzt[(k+1)*CC + t];
            d2 += aS[k+2]*Wzt[(k+2)*CC + t];
            d3 += aS[k+3]*Wzt[(k+3)*CC + t];
        }
        out[((size_t)i*NRES + j)*CC + t] = ((d0+d1)+(d2+d3)) + bzS[t];
        __syncthreads();
    }
}

extern "C" void kernel_launch(void* const* d_in, const int* in_sizes, int n_in,
                              void* d_out, int out_size, void* d_ws, size_t ws_size,
                              hipStream_t stream)
{
    (void)in_sizes; (void)n_in; (void)out_size; (void)ws_size;
    const float* z      = (const float*)d_in[0];
    const float* p      = (const float*)d_in[1];
    const float* mask   = (const float*)d_in[2];
    const float* w_lp   = (const float*)d_in[3];
    const float* b_lp   = (const float*)d_in[4];
    const float* w_rp   = (const float*)d_in[5];
    const float* b_rp   = (const float*)d_in[6];
    const float* w_lg   = (const float*)d_in[7];
    const float* b_lg   = (const float*)d_in[8];
    const float* w_rg   = (const float*)d_in[9];
    const float* b_rg   = (const float*)d_in[10];
    const float* w_z    = (const float*)d_in[11];
    const float* b_z    = (const float*)d_in[12];
    const float* ln_l_w = (const float*)d_in[13];
    const float* ln_l_b = (const float*)d_in[14];
    const float* ln_r_w = (const float*)d_in[15];
    const float* ln_r_b = (const float*)d_in[16];
    const float* ln_o_w = (const float*)d_in[17];
    const float* ln_o_b = (const float*)d_in[18];
    float* out = (float*)d_out;

    float* zl = (float*)d_ws;              // [512][128]
    float* zr = zl + NRES*CC;              // [512][128]

    phaseA_kernel<<<dim3(2*NRES), dim3(512), 0, stream>>>(
        p, z, mask, w_lp, b_lp, w_lg, b_lg, w_rp, b_rp, w_rg, b_rg,
        ln_l_w, ln_l_b, ln_r_w, ln_r_b, zl);

    phaseB_fp32<<<dim3(NRES*8), dim3(128), 0, stream>>>(
        zl, zr, w_z, b_z, ln_o_w, ln_o_b, out);
}

// Round 7
// 301.555 us; speedup vs baseline: 24.9217x; 4.4274x over previous
//
#include <hip/hip_runtime.h>
#include <hip/hip_bf16.h>
#include <math.h>

#define NRES 512
#define CC   128
#define LN_EPS 1e-5f
#define SPLIT_SCALE 1024.0f
#define SPLIT_INV   0.0009765625f

typedef _Float16 half_t;
typedef __attribute__((ext_vector_type(8))) _Float16 f16x8;
typedef __attribute__((ext_vector_type(4))) float f32x4;

__device__ __forceinline__ float sigmoidf_(float x) {
    return 1.0f / (1.0f + expf(-x));
}

// ---------------------------------------------------------------------------
// Phase A (MFMA, barrier-protected): per (side, i):
//   x1[j,:] = maybe_mask * (LN(X[i,j,:]) @ Wp^T + bp)   [split-fp16 -> fp32-grade]
//   g[j,:]  = sigmoid(x1 @ Wg^T + bg)                   [fp16]
//   S[i,:]  = sum_j g*x1                                [fp32]
// sAX tile time-shared A_hi -> A_lo -> X1, with __syncthreads() at every
// hand-off (R6 lesson: no zero-barrier wave-self-containment).
// ---------------------------------------------------------------------------
__global__ __launch_bounds__(512)
void phaseA_kernel(const float* __restrict__ p, const float* __restrict__ z,
                   const float* __restrict__ mask,
                   const float* __restrict__ Wlp, const float* __restrict__ blp,
                   const float* __restrict__ Wlg, const float* __restrict__ blg,
                   const float* __restrict__ Wrp, const float* __restrict__ brp,
                   const float* __restrict__ Wrg, const float* __restrict__ brg,
                   const float* __restrict__ lnlw, const float* __restrict__ lnlb,
                   const float* __restrict__ lnrw, const float* __restrict__ lnrb,
                   float* __restrict__ SL)
{
    __shared__ __align__(16) half_t sWp_hi[CC*CC];
    __shared__ __align__(16) half_t sWp_lo[CC*CC];
    __shared__ __align__(16) half_t sWg  [CC*CC];
    __shared__ __align__(16) half_t sAX  [128*CC];
    __shared__ float sbp[CC], sbg[CC], slnw[CC], slnb[CC];
    __shared__ float smask[NRES];
    __shared__ float sred[8][CC];

    const int t    = threadIdx.x;
    const int side = blockIdx.x >> 9;
    const int i    = blockIdx.x & 511;
    const int lane = t & 63;
    const int w    = t >> 6;

    const float* X   = side ? z   : p;
    const float* Wp  = side ? Wrp : Wlp;
    const float* bp  = side ? brp : blp;
    const float* Wg  = side ? Wrg : Wlg;
    const float* bg  = side ? brg : blg;
    const float* lnw = side ? lnrw : lnlw;
    const float* lnb = side ? lnrb : lnlb;
    const bool   use_mask = (side != 0);

    {
        const int o = t >> 2, q = t & 3;
        const float* wp_row = Wp + o * CC;
        const float* wg_row = Wg + o * CC;
        #pragma unroll
        for (int b = 0; b < 4; ++b) {
            const int blk  = q * 4 + b;
            const int dblk = blk ^ (o & 7);
            f32x4 lo  = *(const f32x4*)(wp_row + blk*8);
            f32x4 hi  = *(const f32x4*)(wp_row + blk*8 + 4);
            f32x4 lo2 = *(const f32x4*)(wg_row + blk*8);
            f32x4 hi2 = *(const f32x4*)(wg_row + blk*8 + 4);
            f16x8 vh, vl, vg;
            #pragma unroll
            for (int e = 0; e < 4; ++e) {
                float w0 = lo[e], w1 = hi[e];
                half_t h0 = (half_t)w0, h1 = (half_t)w1;
                vh[e] = h0; vh[e+4] = h1;
                vl[e]   = (half_t)((w0 - (float)h0) * SPLIT_SCALE);
                vl[e+4] = (half_t)((w1 - (float)h1) * SPLIT_SCALE);
                vg[e]   = (half_t)lo2[e]; vg[e+4] = (half_t)hi2[e];
            }
            *(f16x8*)&sWp_hi[o*CC + dblk*8] = vh;
            *(f16x8*)&sWp_lo[o*CC + dblk*8] = vl;
            *(f16x8*)&sWg  [o*CC + dblk*8] = vg;
        }
    }
    if (t < CC) { sbp[t] = bp[t]; sbg[t] = bg[t]; slnw[t] = lnw[t]; slnb[t] = lnb[t]; }
    if (use_mask) {
        for (int j = t; j < NRES; j += 512) smask[j] = mask[(size_t)i*NRES + j];
    }
    __syncthreads();

    float colacc[8];
    #pragma unroll
    for (int c = 0; c < 8; ++c) colacc[c] = 0.f;

    const int r     = t >> 2;
    const int q     = t & 3;
    const int kq    = lane >> 4;
    const int arow  = (w << 4) + (lane & 15);
    const int drow0 = (w << 4) + (kq << 2);

    for (int chunk = 0; chunk < 4; ++chunk) {
        const int j0 = chunk * 128;

        // --- LN + hi/lo split; hi -> sAX, lo kept in regs ---
        f16x8 alo_sv[4];
        {
            const float* rowp = X + ((size_t)i*NRES + (j0 + r)) * CC + q*32;
            float vals[32];
            float sum = 0.f, sq = 0.f;
            #pragma unroll
            for (int k = 0; k < 8; ++k) {
                f32x4 v4 = *(const f32x4*)(rowp + k*4);
                #pragma unroll
                for (int e = 0; e < 4; ++e) {
                    float x = v4[e];
                    vals[k*4+e] = x;
                    sum += x; sq += x*x;
                }
            }
            sum += __shfl_xor(sum, 1); sum += __shfl_xor(sum, 2);
            sq  += __shfl_xor(sq , 1); sq  += __shfl_xor(sq , 2);
            const float m  = sum * (1.f/CC);
            const float rs = rsqrtf(sq * (1.f/CC) - m*m + LN_EPS);
            #pragma unroll
            for (int b = 0; b < 4; ++b) {
                f16x8 o8;
                #pragma unroll
                for (int e = 0; e < 8; ++e) {
                    const int c = q*32 + b*8 + e;
                    float lnv = (vals[b*8+e] - m) * rs * slnw[c] + slnb[c];
                    half_t h = (half_t)lnv;
                    o8[e] = h;
                    alo_sv[b][e] = (half_t)((lnv - (float)h) * SPLIT_SCALE);
                }
                *(f16x8*)&sAX[r*CC + ((q*4+b) ^ (r & 7))*8] = o8;
            }
        }
        __syncthreads();   // A_hi visible

        f16x8 afh[4];
        #pragma unroll
        for (int kk = 0; kk < 4; ++kk)
            afh[kk] = *(const f16x8*)&sAX[arow*CC + (((kk<<2)+kq) ^ (arow & 7))*8];
        __syncthreads();   // all A_hi reads done

        #pragma unroll
        for (int b = 0; b < 4; ++b)
            *(f16x8*)&sAX[r*CC + ((q*4+b) ^ (r & 7))*8] = alo_sv[b];
        __syncthreads();   // A_lo visible

        f16x8 afl[4];
        #pragma unroll
        for (int kk = 0; kk < 4; ++kk)
            afl[kk] = *(const f16x8*)&sAX[arow*CC + (((kk<<2)+kq) ^ (arow & 7))*8];
        __syncthreads();   // all A_lo reads done; sAX free for X1

        // --- pass 1: x1 = A @ Wp^T + bp (split), mask; store fp16 X1 ---
        float xv[8][4];
        float mrow[4];
        if (use_mask) {
            #pragma unroll
            for (int rr = 0; rr < 4; ++rr) mrow[rr] = smask[j0 + drow0 + rr];
        }
        #pragma unroll
        for (int ct = 0; ct < 8; ++ct) {
            const int ocol = (ct << 4) + (lane & 15);
            f32x4 acc1 = {0.f,0.f,0.f,0.f};
            f32x4 acc2 = {0.f,0.f,0.f,0.f};
            #pragma unroll
            for (int kk = 0; kk < 4; ++kk) {
                const int idx = ocol*CC + (((kk<<2)+kq) ^ (ocol & 7))*8;
                f16x8 whi = *(const f16x8*)&sWp_hi[idx];
                f16x8 wlo = *(const f16x8*)&sWp_lo[idx];
                acc1 = __builtin_amdgcn_mfma_f32_16x16x32_f16(afh[kk], whi, acc1, 0, 0, 0);
                acc2 = __builtin_amdgcn_mfma_f32_16x16x32_f16(afh[kk], wlo, acc2, 0, 0, 0);
                acc2 = __builtin_amdgcn_mfma_f32_16x16x32_f16(afl[kk], whi, acc2, 0, 0, 0);
            }
            const float bias = sbp[ocol];
            #pragma unroll
            for (int rr = 0; rr < 4; ++rr) {
                float x = acc1[rr] + acc2[rr]*SPLIT_INV + bias;
                if (use_mask) x *= mrow[rr];
                xv[ct][rr] = x;
                const int dr = drow0 + rr;
                sAX[dr*CC + (((ocol>>3) ^ (dr & 7))<<3) + (ocol & 7)] = (half_t)x;
            }
        }
        __syncthreads();   // X1 visible

        // --- pass 2: gate + accumulate ---
        f16x8 a2[4];
        #pragma unroll
        for (int kk = 0; kk < 4; ++kk)
            a2[kk] = *(const f16x8*)&sAX[arow*CC + (((kk<<2)+kq) ^ (arow & 7))*8];
        #pragma unroll
        for (int ct = 0; ct < 8; ++ct) {
            const int ocol = (ct << 4) + (lane & 15);
            f32x4 acc = {0.f,0.f,0.f,0.f};
            #pragma unroll
            for (int kk = 0; kk < 4; ++kk) {
                f16x8 bfr = *(const f16x8*)&sWg[ocol*CC + (((kk<<2)+kq) ^ (ocol & 7))*8];
                acc = __builtin_amdgcn_mfma_f32_16x16x32_f16(a2[kk], bfr, acc, 0, 0, 0);
            }
            const float bias = sbg[ocol];
            float part = 0.f;
            #pragma unroll
            for (int rr = 0; rr < 4; ++rr)
                part += sigmoidf_(acc[rr] + bias) * xv[ct][rr];
            part += __shfl_xor(part, 16);
            part += __shfl_xor(part, 32);
            colacc[ct] += part;
        }
        __syncthreads();   // pass-2 reads done before next chunk overwrites sAX
    }

    if (lane < 16) {
        #pragma unroll
        for (int ct = 0; ct < 8; ++ct) sred[w][(ct<<4) + lane] = colacc[ct];
    }
    __syncthreads();
    if (t < CC) {
        float s = 0.f;
        #pragma unroll
        for (int ww = 0; ww < 8; ++ww) s += sred[ww][t];
        SL[((size_t)side*NRES + i)*CC + t] = s;
    }
}

// ---------------------------------------------------------------------------
// Phase B (MFMA, barrier-protected, split-fp16):
//   out[i,j,:] = LN(zl[i] * zr[j]) @ Wz^T + bz
// ---------------------------------------------------------------------------
__global__ __launch_bounds__(512)
void phaseB_kernel(const float* __restrict__ zl, const float* __restrict__ zr,
                   const float* __restrict__ Wz, const float* __restrict__ bz,
                   const float* __restrict__ lnw, const float* __restrict__ lnb,
                   float* __restrict__ out)
{
    __shared__ __align__(16) half_t sW_hi[CC*CC];
    __shared__ __align__(16) half_t sW_lo[CC*CC];
    __shared__ __align__(16) half_t sAX[128*CC];
    __shared__ float szl[CC], sbz[CC], slnw[CC], slnb[CC];

    const int t    = threadIdx.x;
    const int i    = blockIdx.x >> 2;
    const int j0   = (blockIdx.x & 3) * 128;
    const int lane = t & 63;
    const int w    = t >> 6;

    {
        const int o = t >> 2, q = t & 3;
        const float* wrow = Wz + o * CC;
        #pragma unroll
        for (int b = 0; b < 4; ++b) {
            const int blk  = q*4 + b;
            const int dblk = blk ^ (o & 7);
            f32x4 lo = *(const f32x4*)(wrow + blk*8);
            f32x4 hi = *(const f32x4*)(wrow + blk*8 + 4);
            f16x8 vh, vl;
            #pragma unroll
            for (int e = 0; e < 4; ++e) {
                float w0 = lo[e], w1 = hi[e];
                half_t h0 = (half_t)w0, h1 = (half_t)w1;
                vh[e] = h0; vh[e+4] = h1;
                vl[e]   = (half_t)((w0 - (float)h0) * SPLIT_SCALE);
                vl[e+4] = (half_t)((w1 - (float)h1) * SPLIT_SCALE);
            }
            *(f16x8*)&sW_hi[o*CC + dblk*8] = vh;
            *(f16x8*)&sW_lo[o*CC + dblk*8] = vl;
        }
    }
    if (t < CC) { szl[t] = zl[(size_t)i*CC + t]; sbz[t] = bz[t]; slnw[t] = lnw[t]; slnb[t] = lnb[t]; }
    __syncthreads();

    // A = LN(zl[i] * zr[j0+r]), hi -> sAX, lo in regs
    f16x8 alo_sv[4];
    {
        const int r = t >> 2, q = t & 3;
        const float* rowp = zr + (size_t)(j0 + r) * CC + q*32;
        float vals[32];
        float sum = 0.f, sq = 0.f;
        #pragma unroll
        for (int k = 0; k < 8; ++k) {
            f32x4 v4 = *(const f32x4*)(rowp + k*4);
            #pragma unroll
            for (int e = 0; e < 4; ++e) {
                float x = v4[e] * szl[q*32 + k*4 + e];
                vals[k*4+e] = x;
                sum += x; sq += x*x;
            }
        }
        sum += __shfl_xor(sum, 1); sum += __shfl_xor(sum, 2);
        sq  += __shfl_xor(sq , 1); sq  += __shfl_xor(sq , 2);
        const float m  = sum * (1.f/CC);
        const float rs = rsqrtf(sq * (1.f/CC) - m*m + LN_EPS);
        #pragma unroll
        for (int b = 0; b < 4; ++b) {
            f16x8 o8;
            #pragma unroll
            for (int e = 0; e < 8; ++e) {
                const int c = q*32 + b*8 + e;
                float lnv = (vals[b*8+e] - m) * rs * slnw[c] + slnb[c];
                half_t h = (half_t)lnv;
                o8[e] = h;
                alo_sv[b][e] = (half_t)((lnv - (float)h) * SPLIT_SCALE);
            }
            *(f16x8*)&sAX[(t>>2)*CC + ((q*4+b) ^ ((t>>2) & 7))*8] = o8;
        }
    }
    __syncthreads();   // A_hi visible

    const int kq    = lane >> 4;
    const int arow  = (w << 4) + (lane & 15);
    const int drow0 = (w << 4) + (kq << 2);

    f16x8 afh[4];
    #pragma unroll
    for (int kk = 0; kk < 4; ++kk)
        afh[kk] = *(const f16x8*)&sAX[arow*CC + (((kk<<2)+kq) ^ (arow & 7))*8];
    __syncthreads();   // A_hi reads done

    {
        const int r = t >> 2, q = t & 3;
        #pragma unroll
        for (int b = 0; b < 4; ++b)
            *(f16x8*)&sAX[r*CC + ((q*4+b) ^ (r & 7))*8] = alo_sv[b];
    }
    __syncthreads();   // A_lo visible

    f16x8 afl[4];
    #pragma unroll
    for (int kk = 0; kk < 4; ++kk)
        afl[kk] = *(const f16x8*)&sAX[arow*CC + (((kk<<2)+kq) ^ (arow & 7))*8];

    #pragma unroll
    for (int ct = 0; ct < 8; ++ct) {
        const int ocol = (ct << 4) + (lane & 15);
        f32x4 acc1 = {0.f,0.f,0.f,0.f};
        f32x4 acc2 = {0.f,0.f,0.f,0.f};
        #pragma unroll
        for (int kk = 0; kk < 4; ++kk) {
            const int idx = ocol*CC + (((kk<<2)+kq) ^ (ocol & 7))*8;
            f16x8 whi = *(const f16x8*)&sW_hi[idx];
            f16x8 wlo = *(const f16x8*)&sW_lo[idx];
            acc1 = __builtin_amdgcn_mfma_f32_16x16x32_f16(afh[kk], whi, acc1, 0, 0, 0);
            acc2 = __builtin_amdgcn_mfma_f32_16x16x32_f16(afh[kk], wlo, acc2, 0, 0, 0);
            acc2 = __builtin_amdgcn_mfma_f32_16x16x32_f16(afl[kk], whi, acc2, 0, 0, 0);
        }
        const float bias = sbz[ocol];
        #pragma unroll
        for (int rr = 0; rr < 4; ++rr) {
            const size_t j = (size_t)(j0 + drow0 + rr);
            out[((size_t)i*NRES + j)*CC + ocol] = acc1[rr] + acc2[rr]*SPLIT_INV + bias;
        }
    }
}

extern "C" void kernel_launch(void* const* d_in, const int* in_sizes, int n_in,
                              void* d_out, int out_size, void* d_ws, size_t ws_size,
                              hipStream_t stream)
{
    (void)in_sizes; (void)n_in; (void)out_size; (void)ws_size;
    const float* z      = (const float*)d_in[0];
    const float* p      = (const float*)d_in[1];
    const float* mask   = (const float*)d_in[2];
    const float* w_lp   = (const float*)d_in[3];
    const float* b_lp   = (const float*)d_in[4];
    const float* w_rp   = (const float*)d_in[5];
    const float* b_rp   = (const float*)d_in[6];
    const float* w_lg   = (const float*)d_in[7];
    const float* b_lg   = (const float*)d_in[8];
    const float* w_rg   = (const float*)d_in[9];
    const float* b_rg   = (const float*)d_in[10];
    const float* w_z    = (const float*)d_in[11];
    const float* b_z    = (const float*)d_in[12];
    const float* ln_l_w = (const float*)d_in[13];
    const float* ln_l_b = (const float*)d_in[14];
    const float* ln_r_w = (const float*)d_in[15];
    const float* ln_r_b = (const float*)d_in[16];
    const float* ln_o_w = (const float*)d_in[17];
    const float* ln_o_b = (const float*)d_in[18];
    float* out = (float*)d_out;

    float* zl = (float*)d_ws;              // [512][128]
    float* zr = zl + NRES*CC;              // [512][128]

    phaseA_kernel<<<dim3(2*NRES), dim3(512), 0, stream>>>(
        p, z, mask, w_lp, b_lp, w_lg, b_lg, w_rp, b_rp, w_rg, b_rg,
        ln_l_w, ln_l_b, ln_r_w, ln_r_b, zl);

    phaseB_kernel<<<dim3(NRES*4), dim3(512), 0, stream>>>(
        zl, zr, w_z, b_z, ln_o_w, ln_o_b, out);
}